// Round 5
// baseline (264.315 us; speedup 1.0000x reference)
//
#include <hip/hip_runtime.h>
#include <stdint.h>

typedef unsigned short u16;
typedef unsigned int   u32;
typedef short bf16x8 __attribute__((ext_vector_type(8)));   // 8 bf16 in 4 VGPRs
typedef u16   u16x8  __attribute__((ext_vector_type(8)));
typedef u16   u16x4  __attribute__((ext_vector_type(4)));
typedef float f32x4  __attribute__((ext_vector_type(4)));

#define B_   2
#define S_   2048
#define HQ_  32
#define HKV_ 8
#define D_   128
// SCALE * log2(e): scores computed directly in log2 domain (exp -> v_exp_f32)
#define SC2  0.1275174457530659f

// workspace (bf16 elems, 16.8 MB): Kr [B][HKV][S][D] roped K; Vt [B][HKV][D][S]
#define KR_ELEMS (B_*HKV_*S_*D_)

#define KT_BLOCKS ((B_*S_*HKV_*16) / 256)     // 2048
#define VT_BLOCKS (B_*HKV_*(S_/64))           // 512

// XOR swizzle on LDS byte offsets: key = row bits [9:7] -> flip slot bits [6:4].
#define SWZ(x) ((x) ^ (((x) >> 3) & 0x70))

__device__ __forceinline__ float b2f(u16 x) { return __uint_as_float(((u32)x) << 16); }
__device__ __forceinline__ u16 f2b(float f) {
  u32 u = __float_as_uint(f);
  return (u16)((u + 0x7FFFu + ((u >> 16) & 1u)) >> 16);   // RTNE
}
__device__ __forceinline__ bool is_f32(const void* cs) {
  return ((const u32*)cs)[0] == 0x3F800000u;   // cos[0][0] == 1.0f
}

#if __has_builtin(__builtin_amdgcn_exp2f)
#define EXP2(x) __builtin_amdgcn_exp2f(x)
#else
#define EXP2(x) exp2f(x)
#endif

// gfx950 dual-dest lane swaps. Builtin returns {new_vdst, new_vsrc}.
// Semantics (HW-verified R4 pass):
//   v_permlane32_swap a,b: a' = [a0,a1,b0,b1], b' = [a2,a3,b2,b3]  (16-lane quads)
//   v_permlane16_swap a,b: a' = [a0,b0,a2,b2], b' = [a1,b1,a3,b3]
__device__ __forceinline__ void pl32(u32& a, u32& b) {
  auto r = __builtin_amdgcn_permlane32_swap((int)a, (int)b, false, false);
  a = (u32)r[0]; b = (u32)r[1];
}
__device__ __forceinline__ void pl16(u32& a, u32& b) {
  auto r = __builtin_amdgcn_permlane16_swap((int)a, (int)b, false, false);
  a = (u32)r[0]; b = (u32)r[1];
}
// cross-quad reductions (lanes lq, lq+16, lq+32, lq+48) without ds ops
__device__ __forceinline__ float qredmax(float x) {
  u32 a = __float_as_uint(x), b = a;
  pl16(a, b);
  float m = fmaxf(__uint_as_float(a), __uint_as_float(b));
  u32 c = __float_as_uint(m), d = c;
  pl32(c, d);
  return fmaxf(__uint_as_float(c), __uint_as_float(d));
}
__device__ __forceinline__ float qredsum(float x) {
  u32 a = __float_as_uint(x), b = a;
  pl16(a, b);
  float m = __uint_as_float(a) + __uint_as_float(b);
  u32 c = __float_as_uint(m), d = c;
  pl32(c, d);
  return __uint_as_float(c) + __uint_as_float(d);
}
__device__ __forceinline__ u32 cvtpk(float lo, float hi) {
  u32 r;
  asm("v_cvt_pk_bf16_f32 %0, %1, %2" : "=v"(r) : "v"(lo), "v"(hi));
  return r;
}

__device__ __forceinline__ void gload16(const u16* g, u16* l) {
  __builtin_amdgcn_global_load_lds(
      (const __attribute__((address_space(1))) u32*)g,
      (__attribute__((address_space(3))) u32*)l, 16, 0, 0);
}

// ---------------- pre-pass: RoPE(K) -> Kr, transpose(V) -> Vt (both bf16) ----
__global__ __launch_bounds__(256) void rope_pre(
    const void* __restrict__ kin, const void* __restrict__ vin,
    const void* __restrict__ cs, const void* __restrict__ sn, u16* __restrict__ ws)
{
  const bool f32 = is_f32(cs);
  const int bx = blockIdx.x;
  const int t  = threadIdx.x;
  __shared__ u16 tile[64 * 136];   // V transpose tile, pad 136

  if (bx < KT_BLOCKS) {
    int tid = bx*256 + t;
    int j4 = tid & 15;                 // d2 = 4*j4 .. +3
    int s  = (tid >> 4) & (S_ - 1);
    int h  = (tid >> 15) & (HKV_ - 1);
    int b  = tid >> 18;
    int gi = ((b*S_ + s)*HKV_ + h)*D_ + 4*j4;
    int ci = s*D_ + 4*j4;
    float xa[4], xb[4], c[4], si[4];
    if (f32) {
      const float* kf = (const float*)kin;
      f32x4 a0 = *(const f32x4*)(kf + gi);
      f32x4 b0 = *(const f32x4*)(kf + gi + 64);
      f32x4 c0 = *(const f32x4*)((const float*)cs + ci);
      f32x4 s0 = *(const f32x4*)((const float*)sn + ci);
#pragma unroll
      for (int e = 0; e < 4; ++e) { xa[e]=a0[e]; xb[e]=b0[e]; c[e]=c0[e]; si[e]=s0[e]; }
    } else {
      const u16* kb16 = (const u16*)kin;
      u16x4 a0 = *(const u16x4*)(kb16 + gi);
      u16x4 b0 = *(const u16x4*)(kb16 + gi + 64);
      u16x4 c0 = *(const u16x4*)((const u16*)cs + ci);
      u16x4 s0 = *(const u16x4*)((const u16*)sn + ci);
#pragma unroll
      for (int e = 0; e < 4; ++e) { xa[e]=b2f(a0[e]); xb[e]=b2f(b0[e]); c[e]=b2f(c0[e]); si[e]=b2f(s0[e]); }
    }
    u16 o0[4], o1[4];
#pragma unroll
    for (int e = 0; e < 4; ++e) {
      o0[e] = f2b(xa[e]*c[e] - xb[e]*si[e]);   // d < 64
      o1[e] = f2b(xb[e]*c[e] + xa[e]*si[e]);   // d >= 64 (cos[d]==cos[d+64])
    }
    int oi = ((b*HKV_ + h)*S_ + s)*D_ + 4*j4;
    *(u16x4*)(ws + oi)      = *(u16x4*)o0;
    *(u16x4*)(ws + oi + 64) = *(u16x4*)o1;
  } else {
    int vb = bx - KT_BLOCKS;           // 0..511
    int sb = vb & 31;                  // 64-row s-block
    int h  = (vb >> 5) & (HKV_ - 1);
    int b  = vb >> 8;
    int s0 = sb * 64;
#pragma unroll
    for (int it = 0; it < 8; ++it) {
      int task = it*256 + t;           // 2048 = 64 rows x 32 col-groups
      int c4 = task & 31;
      int r  = task >> 5;
      int gi = ((b*S_ + s0 + r)*HKV_ + h)*D_ + 4*c4;
      u16 e[4];
      if (f32) {
        f32x4 a = *(const f32x4*)((const float*)vin + gi);
#pragma unroll
        for (int j = 0; j < 4; ++j) e[j] = f2b(a[j]);
      } else {
        u16x4 a = *(const u16x4*)((const u16*)vin + gi);
#pragma unroll
        for (int j = 0; j < 4; ++j) e[j] = a[j];
      }
      *(u16x4*)&tile[r*136 + 4*c4] = *(u16x4*)e;
    }
    __syncthreads();
    u32* vtd = (u32*)(ws + KR_ELEMS) + (b*HKV_ + h)*D_*(S_/2);
#pragma unroll
    for (int it = 0; it < 16; ++it) {
      int task = it*256 + t;           // 4096 = 128 d x 32 sp
      int sp = task & 31, d = task >> 5;
      u32 lo = tile[(2*sp)*136 + d];
      u32 hi = tile[(2*sp + 1)*136 + d];
      vtd[d*(S_/2) + s0/2 + sp] = lo | (hi << 16);
    }
  }
}

// ---------------- flash attention, S^T formulation, 2x q-blocked ----------------
// 1024 blocks x 4 waves; block = one 128-query tile; wave w owns rows
// 32w..32w+31 as two 16-q groups (A: +lq, B: +16+lq). Each K/V fragment read
// feeds both groups -> LDS traffic per query halved vs 16-q waves. Blocks are
// dispatched long-first (qt descending) to absorb causal load imbalance.
// Wave w computes only kb <= diag (=4qt+w); masks only AT the diagonal where
// the mask is the position-independent pattern quad*4+r > lq.
__global__ __launch_bounds__(256, 3) void flash_attn(
    const void* __restrict__ qg, const void* __restrict__ cs, const void* __restrict__ sn,
    const u16* __restrict__ ws, float* __restrict__ out)
{
  // LDS bytes: buf0 {K@0, V@8192}, buf1 {K@16384, V@24576} = 32768 B total.
  // Q staging [4][128][32] = 32 KB overlaps both buffers, consumed pre-loop.
  __shared__ __attribute__((aligned(16))) u16 lds[16384];
  char* ldsc = (char*)lds;

  const bool f32 = is_f32(cs);
  const int t = threadIdx.x;
  const int lane = t & 63, w = t >> 6;
  const int lq = lane & 15, quad = lane >> 4;

  // One per-lane swizzled offset shared by ALL K/V/Q fragment reads; the XOR
  // key (lq>>1)&7 is invariant to +16/+32-row and chunk offsets (bits >=10).
  const int kq = (lq*64 + quad*16) ^ (((lq >> 1) & 7) << 4);

  // XCD swizzle: bx%8 = XCD; 2 (b,kvh) combos per XCD; qt descending (long first)
  int bx = blockIdx.x;
  int g = bx & 7, ii = bx >> 3;
  int combo = g*2 + (ii >> 6);
  int b = combo >> 3, kvh = combo & 7;
  int rr = ii & 63;
  int h   = kvh*4 + (rr & 3);
  int qt  = 15 - (rr >> 2);            // 128-q tile index, big tiles dispatch first
  int q0  = qt * 128;
  const int nkb  = 4*qt + 4;           // causal: keys [0, q0+128)
  const int diag = 4*qt + w;           // wave w's diagonal tile

  const u16* Kr = ws + (b*HKV_ + kvh)*S_*D_;
  const u16* Vt = ws + KR_ELEMS + (b*HKV_ + kvh)*D_*S_;

  // staging sources (linear LDS dest, inverse-swizzled global source — rule #21)
  const int aK0 = t*16, aK1 = t*16 + 4096;
  const int lA0 = SWZ(aK0), lA1 = SWZ(aK1);
  const u16* kg0 = Kr + ((lA0 >> 6) & 31)*D_ + (lA0 >> 11)*32 + ((lA0 >> 4) & 3)*8;
  const u16* kg1 = Kr + ((lA1 >> 6) & 31)*D_ + (lA1 >> 11)*32 + ((lA1 >> 4) & 3)*8;
  const u16* vg0 = Vt + (lA0 >> 6)*S_ + ((lA0 >> 4) & 3)*8;
  const u16* vg1 = Vt + (lA1 >> 6)*S_ + ((lA1 >> 4) & 3)*8;

#define STAGE(bufbyte, n0v) do {                                   \
    gload16(kg0 + (n0v)*D_, (u16*)(ldsc + (bufbyte) + aK0));       \
    gload16(kg1 + (n0v)*D_, (u16*)(ldsc + (bufbyte) + aK1));       \
    gload16(vg0 + (n0v),    (u16*)(ldsc + (bufbyte) + 8192 + aK0));\
    gload16(vg1 + (n0v),    (u16*)(ldsc + (bufbyte) + 8192 + aK1));\
  } while (0)

  // ---- stage Q tile (128 rows): RoPE + SC2 folded in, swizzled stores ----
  // chunk-major [c][128 row][32 e]: chunk stride 8192 B, row stride 64 B
#pragma unroll
  for (int it = 0; it < 4; ++it) {
    int tp = it*256 + t;
    int row = tp >> 3, j = tp & 7;          // 8 threads/row, 16B loads
    int qbase = ((b*S_ + q0 + row)*HQ_ + h)*D_ + 8*j;
    int cbase = (q0 + row)*D_ + 8*j;
    float a[8], bb[8], cc[8], ssv[8];
    if (f32) {
      const float* qf32 = (const float*)qg;
      f32x4 a0 = *(const f32x4*)(qf32 + qbase);
      f32x4 a1 = *(const f32x4*)(qf32 + qbase + 4);
      f32x4 b0 = *(const f32x4*)(qf32 + qbase + 64);
      f32x4 b1 = *(const f32x4*)(qf32 + qbase + 68);
      f32x4 c0 = *(const f32x4*)((const float*)cs + cbase);
      f32x4 c1 = *(const f32x4*)((const float*)cs + cbase + 4);
      f32x4 s0 = *(const f32x4*)((const float*)sn + cbase);
      f32x4 s1 = *(const f32x4*)((const float*)sn + cbase + 4);
#pragma unroll
      for (int e = 0; e < 4; ++e) {
        a[e] = a0[e];  a[4+e] = a1[e];  bb[e] = b0[e]; bb[4+e] = b1[e];
        cc[e] = c0[e]; cc[4+e] = c1[e]; ssv[e] = s0[e]; ssv[4+e] = s1[e];
      }
    } else {
      const u16* qb16 = (const u16*)qg;
      u16x8 xa = *(const u16x8*)(qb16 + qbase);
      u16x8 xb = *(const u16x8*)(qb16 + qbase + 64);
      u16x8 cv = *(const u16x8*)((const u16*)cs + cbase);
      u16x8 sv = *(const u16x8*)((const u16*)sn + cbase);
#pragma unroll
      for (int e = 0; e < 8; ++e) {
        a[e] = b2f(xa[e]); bb[e] = b2f(xb[e]);
        cc[e] = b2f(cv[e]); ssv[e] = b2f(sv[e]);
      }
    }
    u16 o0[8], o1[8];
#pragma unroll
    for (int e = 0; e < 8; ++e) {
      float C2 = cc[e]*SC2, S2 = ssv[e]*SC2;
      o0[e] = f2b(a[e]*C2 - bb[e]*S2);    // d = 8j+e   (pre-scaled)
      o1[e] = f2b(bb[e]*C2 + a[e]*S2);    // d = 64+8j+e
    }
    int A0 = (j >> 2)*8192 + row*64 + (j & 3)*16;   // logical byte (chunks 0,1)
    int A1 = A0 + 16384;                            // chunks 2,3
    *(u16x8*)(ldsc + SWZ(A0)) = *(u16x8*)o0;
    *(u16x8*)(ldsc + SWZ(A1)) = *(u16x8*)o1;
  }
  __syncthreads();
  bf16x8 qfA[4], qfB[4];
#pragma unroll
  for (int c = 0; c < 4; ++c) {
    qfA[c] = *(const bf16x8*)(ldsc + c*8192 + w*2048 + kq);          // rows 32w+lq
    qfB[c] = *(const bf16x8*)(ldsc + c*8192 + w*2048 + 1024 + kq);   // rows 32w+16+lq
  }
  asm volatile("s_waitcnt lgkmcnt(0)" ::: "memory");   // Q in regs
  __syncthreads();                                     // ...for ALL waves

  f32x4 oA[8], oB[8];
#pragma unroll
  for (int dt = 0; dt < 8; ++dt) { oA[dt] = (f32x4){0,0,0,0}; oB[dt] = (f32x4){0,0,0,0}; }
  float mA = -1e30f, lA = 0.f, mB = -1e30f, lB = 0.f;
  const int qrowA = q0 + 32*w + lq;      // group B row = qrowA + 16

  STAGE(0, 0);                           // prologue: tile 0 -> buf0

  for (int kb = 0; kb < nkb; ++kb) {
    const int cur = kb & 1;
    // (A) all waves done reading buf[cur^1] before re-stage
    asm volatile("" ::: "memory");
    __builtin_amdgcn_s_barrier();
    asm volatile("" ::: "memory");
    if (kb + 1 < nkb) {
      STAGE((cur ^ 1) << 14, (kb + 1)*32);
      asm volatile("s_waitcnt vmcnt(4)" ::: "memory");  // tile kb landed
    } else {
      asm volatile("s_waitcnt vmcnt(0)" ::: "memory");
    }
    __builtin_amdgcn_s_barrier();        // (B) tile kb resident for all waves
    asm volatile("" ::: "memory");

    if (kb > diag) continue;             // fully-masked for this wave: barriers only

    const char* tb = ldsc + (cur << 14) + kq;   // single per-iter base

    // ---- S^T = K Q^T, both q-groups share each K fragment ----
    f32x4 sA0 = {0,0,0,0}, sA1 = {0,0,0,0}, sB0 = {0,0,0,0}, sB1 = {0,0,0,0};
#pragma unroll
    for (int c = 0; c < 4; ++c) {
      bf16x8 k0 = *(const bf16x8*)(tb + c*2048);          // keys lq
      bf16x8 k1 = *(const bf16x8*)(tb + c*2048 + 1024);   // keys 16+lq
      sA0 = __builtin_amdgcn_mfma_f32_16x16x32_bf16(k0, qfA[c], sA0, 0, 0, 0);
      sA1 = __builtin_amdgcn_mfma_f32_16x16x32_bf16(k1, qfA[c], sA1, 0, 0, 0);
      sB0 = __builtin_amdgcn_mfma_f32_16x16x32_bf16(k0, qfB[c], sB0, 0, 0, 0);
      sB1 = __builtin_amdgcn_mfma_f32_16x16x32_bf16(k1, qfB[c], sB1, 0, 0, 0);
    }

    float a0[4], a1[4], b0[4], b1[4];
#pragma unroll
    for (int r = 0; r < 4; ++r) { a0[r]=sA0[r]; a1[r]=sA1[r]; b0[r]=sB0[r]; b1[r]=sB1[r]; }
    if (kb == diag) {
      // n0 == q0+32w here: key = n0+quad*4+r(+16); qrowA = n0+lq, qrowB = n0+16+lq.
      // -> a0: mask quad*4+r > lq; a1: all masked; b0: never masked; b1: like a0.
#pragma unroll
      for (int r = 0; r < 4; ++r) {
        bool over = (quad*4 + r > lq);
        if (over) a0[r] = -1e30f;
        a1[r] = -1e30f;
        if (over) b1[r] = -1e30f;
      }
    }

    // ---- online softmax per group (qred: column across 4 quads) ----
    float mxA = fmaxf(fmaxf(fmaxf(a0[0],a0[1]), fmaxf(a0[2],a0[3])),
                      fmaxf(fmaxf(a1[0],a1[1]), fmaxf(a1[2],a1[3])));
    float mxB = fmaxf(fmaxf(fmaxf(b0[0],b0[1]), fmaxf(b0[2],b0[3])),
                      fmaxf(fmaxf(b1[0],b1[1]), fmaxf(b1[2],b1[3])));
    mxA = qredmax(mxA);
    mxB = qredmax(mxB);
    // T13 defer-rescale (11.5 log2 == 8 nats), one branch for both groups
    if (!__all((mxA - mA <= 11.5f) && (mxB - mB <= 11.5f))) {
      float mnA = fmaxf(mA, mxA), alA = EXP2(mA - mnA);
      float mnB = fmaxf(mB, mxB), alB = EXP2(mB - mnB);
      lA *= alA; lB *= alB;
#pragma unroll
      for (int dt = 0; dt < 8; ++dt) {
#pragma unroll
        for (int r = 0; r < 4; ++r) { oA[dt][r] *= alA; oB[dt][r] *= alB; }
      }
      mA = mnA; mB = mnB;
    }
    float pA0[4], pA1[4], pB0[4], pB1[4];
    float rsA = 0.f, rsB = 0.f;
#pragma unroll
    for (int r = 0; r < 4; ++r) {
      pA0[r] = EXP2(a0[r] - mA); pA1[r] = EXP2(a1[r] - mA);
      pB0[r] = EXP2(b0[r] - mB); pB1[r] = EXP2(b1[r] - mB);
      rsA += pA0[r] + pA1[r];    rsB += pB0[r] + pB1[r];
    }
    lA += qredsum(rsA);
    lB += qredsum(rsB);

    // ---- P^T in-register (proven R4 sequence), per group ----
    u32 YA0 = cvtpk(pA0[0], pA0[1]), YA1 = cvtpk(pA0[2], pA0[3]);
    u32 ZA0 = cvtpk(pA1[0], pA1[1]), ZA1 = cvtpk(pA1[2], pA1[3]);
    pl32(YA0, ZA0); pl16(YA0, ZA0);          // YA0 = w0, ZA0 = w2
    pl32(YA1, ZA1); pl16(YA1, ZA1);          // YA1 = w1, ZA1 = w3
    u32 YB0 = cvtpk(pB0[0], pB0[1]), YB1 = cvtpk(pB0[2], pB0[3]);
    u32 ZB0 = cvtpk(pB1[0], pB1[1]), ZB1 = cvtpk(pB1[2], pB1[3]);
    pl32(YB0, ZB0); pl16(YB0, ZB0);
    pl32(YB1, ZB1); pl16(YB1, ZB1);
    union { u32 wd[4]; bf16x8 v; } puA, puB;
    puA.wd[0] = YA0; puA.wd[1] = YA1; puA.wd[2] = ZA0; puA.wd[3] = ZA1;
    puB.wd[0] = YB0; puB.wd[1] = YB1; puB.wd[2] = ZB0; puB.wd[3] = ZB1;
    bf16x8 pfA = puA.v, pfB = puB.v;

    // ---- O^T += V^T P^T, both groups share each V fragment ----
#pragma unroll
    for (int dt = 0; dt < 8; ++dt) {
      bf16x8 vf = *(const bf16x8*)(tb + 8192 + dt*1024);
      oA[dt] = __builtin_amdgcn_mfma_f32_16x16x32_bf16(vf, pfA, oA[dt], 0, 0, 0);
      oB[dt] = __builtin_amdgcn_mfma_f32_16x16x32_bf16(vf, pfB, oB[dt], 0, 0, 0);
    }
  }

  // ---- epilogue: O^T/l -> out [B][S][HQ][D] f32; 4 consecutive d per lane ----
  float invA = 1.0f / lA, invB = 1.0f / lB;
  float* opA = out + ((b*S_ + qrowA)*HQ_ + h)*D_ + quad*4;
  float* opB = opA + 16*HQ_*D_;          // qrowB = qrowA + 16
#pragma unroll
  for (int dt = 0; dt < 8; ++dt) {
    f32x4 va = { oA[dt][0]*invA, oA[dt][1]*invA, oA[dt][2]*invA, oA[dt][3]*invA };
    f32x4 vb = { oB[dt][0]*invB, oB[dt][1]*invB, oB[dt][2]*invB, oB[dt][3]*invB };
    *(f32x4*)(opA + dt*16) = va;
    *(f32x4*)(opB + dt*16) = vb;
  }
#undef STAGE
}

extern "C" void kernel_launch(void* const* d_in, const int* in_sizes, int n_in,
                              void* d_out, int out_size, void* d_ws, size_t ws_size,
                              hipStream_t stream) {
  const void* q  = d_in[0];
  const void* k  = d_in[1];
  const void* v  = d_in[2];
  const void* cs = d_in[3];
  const void* sn = d_in[4];
  // d_in[5] (mask) and d_in[6] (scale) are applied analytically in-kernel.
  u16*   ws  = (u16*)d_ws;     // needs 16.8 MB
  float* out = (float*)d_out;  // reference output dtype is float32

  rope_pre<<<KT_BLOCKS + VT_BLOCKS, 256, 0, stream>>>(k, v, cs, sn, ws);
  flash_attn<<<B_*HQ_*(S_/128), 256, 0, stream>>>(q, cs, sn, ws, out);
}

// Round 6
// 256.184 us; speedup vs baseline: 1.0317x; 1.0317x over previous
//
#include <hip/hip_runtime.h>
#include <stdint.h>

typedef unsigned short u16;
typedef unsigned int   u32;
typedef short bf16x8 __attribute__((ext_vector_type(8)));   // 8 bf16 in 4 VGPRs
typedef u16   u16x8  __attribute__((ext_vector_type(8)));
typedef u16   u16x4  __attribute__((ext_vector_type(4)));
typedef float f32x4  __attribute__((ext_vector_type(4)));

#define B_   2
#define S_   2048
#define HQ_  32
#define HKV_ 8
#define D_   128
// SCALE * log2(e): scores computed directly in log2 domain (exp -> v_exp_f32)
#define SC2  0.1275174457530659f

// workspace (bf16 elems, 16.8 MB): Kr [B][HKV][S][D] roped K; Vt [B][HKV][D][S]
#define KR_ELEMS (B_*HKV_*S_*D_)

#define KT_BLOCKS ((B_*S_*HKV_*16) / 256)     // 2048
#define VT_BLOCKS (B_*HKV_*(S_/64))           // 512

// XOR swizzle on LDS byte offsets: key = row bits [9:7] -> flip slot bits [6:4].
#define SWZ(x) ((x) ^ (((x) >> 3) & 0x70))

__device__ __forceinline__ float b2f(u16 x) { return __uint_as_float(((u32)x) << 16); }
__device__ __forceinline__ u16 f2b(float f) {
  u32 u = __float_as_uint(f);
  return (u16)((u + 0x7FFFu + ((u >> 16) & 1u)) >> 16);   // RTNE
}
__device__ __forceinline__ bool is_f32(const void* cs) {
  return ((const u32*)cs)[0] == 0x3F800000u;   // cos[0][0] == 1.0f
}

#if __has_builtin(__builtin_amdgcn_exp2f)
#define EXP2(x) __builtin_amdgcn_exp2f(x)
#else
#define EXP2(x) exp2f(x)
#endif

// gfx950 dual-dest lane swaps. Builtin returns {new_vdst, new_vsrc}.
// Semantics (HW-verified R4 pass):
//   v_permlane32_swap a,b: a' = [a0,a1,b0,b1], b' = [a2,a3,b2,b3]  (16-lane quads)
//   v_permlane16_swap a,b: a' = [a0,b0,a2,b2], b' = [a1,b1,a3,b3]
__device__ __forceinline__ void pl32(u32& a, u32& b) {
  auto r = __builtin_amdgcn_permlane32_swap((int)a, (int)b, false, false);
  a = (u32)r[0]; b = (u32)r[1];
}
__device__ __forceinline__ void pl16(u32& a, u32& b) {
  auto r = __builtin_amdgcn_permlane16_swap((int)a, (int)b, false, false);
  a = (u32)r[0]; b = (u32)r[1];
}
// cross-quad reductions (lanes lq, lq+16, lq+32, lq+48) without ds ops
__device__ __forceinline__ float qredmax(float x) {
  u32 a = __float_as_uint(x), b = a;
  pl16(a, b);
  float m = fmaxf(__uint_as_float(a), __uint_as_float(b));
  u32 c = __float_as_uint(m), d = c;
  pl32(c, d);
  return fmaxf(__uint_as_float(c), __uint_as_float(d));
}
__device__ __forceinline__ float qredsum(float x) {
  u32 a = __float_as_uint(x), b = a;
  pl16(a, b);
  float m = __uint_as_float(a) + __uint_as_float(b);
  u32 c = __float_as_uint(m), d = c;
  pl32(c, d);
  return __uint_as_float(c) + __uint_as_float(d);
}
__device__ __forceinline__ u32 cvtpk(float lo, float hi) {
  u32 r;
  asm("v_cvt_pk_bf16_f32 %0, %1, %2" : "=v"(r) : "v"(lo), "v"(hi));
  return r;
}

__device__ __forceinline__ void gload16(const u16* g, u16* l) {
  __builtin_amdgcn_global_load_lds(
      (const __attribute__((address_space(1))) u32*)g,
      (__attribute__((address_space(3))) u32*)l, 16, 0, 0);
}

// ---------------- pre-pass: RoPE(K) -> Kr, transpose(V) -> Vt (both bf16) ----
__global__ __launch_bounds__(256) void rope_pre(
    const void* __restrict__ kin, const void* __restrict__ vin,
    const void* __restrict__ cs, const void* __restrict__ sn, u16* __restrict__ ws)
{
  const bool f32 = is_f32(cs);
  const int bx = blockIdx.x;
  const int t  = threadIdx.x;
  __shared__ u16 tile[64 * 136];   // V transpose tile, pad 136

  if (bx < KT_BLOCKS) {
    int tid = bx*256 + t;
    int j4 = tid & 15;                 // d2 = 4*j4 .. +3
    int s  = (tid >> 4) & (S_ - 1);
    int h  = (tid >> 15) & (HKV_ - 1);
    int b  = tid >> 18;
    int gi = ((b*S_ + s)*HKV_ + h)*D_ + 4*j4;
    int ci = s*D_ + 4*j4;
    float xa[4], xb[4], c[4], si[4];
    if (f32) {
      const float* kf = (const float*)kin;
      f32x4 a0 = *(const f32x4*)(kf + gi);
      f32x4 b0 = *(const f32x4*)(kf + gi + 64);
      f32x4 c0 = *(const f32x4*)((const float*)cs + ci);
      f32x4 s0 = *(const f32x4*)((const float*)sn + ci);
#pragma unroll
      for (int e = 0; e < 4; ++e) { xa[e]=a0[e]; xb[e]=b0[e]; c[e]=c0[e]; si[e]=s0[e]; }
    } else {
      const u16* kb16 = (const u16*)kin;
      u16x4 a0 = *(const u16x4*)(kb16 + gi);
      u16x4 b0 = *(const u16x4*)(kb16 + gi + 64);
      u16x4 c0 = *(const u16x4*)((const u16*)cs + ci);
      u16x4 s0 = *(const u16x4*)((const u16*)sn + ci);
#pragma unroll
      for (int e = 0; e < 4; ++e) { xa[e]=b2f(a0[e]); xb[e]=b2f(b0[e]); c[e]=b2f(c0[e]); si[e]=b2f(s0[e]); }
    }
    u16 o0[4], o1[4];
#pragma unroll
    for (int e = 0; e < 4; ++e) {
      o0[e] = f2b(xa[e]*c[e] - xb[e]*si[e]);   // d < 64
      o1[e] = f2b(xb[e]*c[e] + xa[e]*si[e]);   // d >= 64 (cos[d]==cos[d+64])
    }
    int oi = ((b*HKV_ + h)*S_ + s)*D_ + 4*j4;
    *(u16x4*)(ws + oi)      = *(u16x4*)o0;
    *(u16x4*)(ws + oi + 64) = *(u16x4*)o1;
  } else {
    int vb = bx - KT_BLOCKS;           // 0..511
    int sb = vb & 31;                  // 64-row s-block
    int h  = (vb >> 5) & (HKV_ - 1);
    int b  = vb >> 8;
    int s0 = sb * 64;
#pragma unroll
    for (int it = 0; it < 8; ++it) {
      int task = it*256 + t;           // 2048 = 64 rows x 32 col-groups
      int c4 = task & 31;
      int r  = task >> 5;
      int gi = ((b*S_ + s0 + r)*HKV_ + h)*D_ + 4*c4;
      u16 e[4];
      if (f32) {
        f32x4 a = *(const f32x4*)((const float*)vin + gi);
#pragma unroll
        for (int j = 0; j < 4; ++j) e[j] = f2b(a[j]);
      } else {
        u16x4 a = *(const u16x4*)((const u16*)vin + gi);
#pragma unroll
        for (int j = 0; j < 4; ++j) e[j] = a[j];
      }
      *(u16x4*)&tile[r*136 + 4*c4] = *(u16x4*)e;
    }
    __syncthreads();
    u32* vtd = (u32*)(ws + KR_ELEMS) + (b*HKV_ + h)*D_*(S_/2);
#pragma unroll
    for (int it = 0; it < 16; ++it) {
      int task = it*256 + t;           // 4096 = 128 d x 32 sp
      int sp = task & 31, d = task >> 5;
      u32 lo = tile[(2*sp)*136 + d];
      u32 hi = tile[(2*sp + 1)*136 + d];
      vtd[d*(S_/2) + s0/2 + sp] = lo | (hi << 16);
    }
  }
}

// ---------------- flash attention, S^T formulation ----------------
// R4 structure (proven 122us): 1024 blocks x 4 waves, paired Q-tiles
// {qbp, 31-qbp} -> uniform 68 iters/block. This round: single barrier per
// K-tile (T3 minimum 2-phase: STAGE next -> compute cur -> vmcnt(0)+barrier)
// instead of two, and s_setprio(1) around the MFMA clusters (T5).
__global__ __launch_bounds__(256, 4) void flash_attn(
    const void* __restrict__ qg, const void* __restrict__ cs, const void* __restrict__ sn,
    const u16* __restrict__ ws, float* __restrict__ out)
{
  // LDS bytes: buf0 {K@0, V@8192}, buf1 {K@16384, V@24576} = 32768 B total.
  // Q staging [4][64][32] overlaps buf0 (bytes 0..16383), consumed pre-loop.
  __shared__ __attribute__((aligned(16))) u16 lds[16384];
  char* ldsc = (char*)lds;

  const bool f32 = is_f32(cs);
  const int t = threadIdx.x;
  const int lane = t & 63, w = t >> 6;
  const int lq = lane & 15, quad = lane >> 4;

  // One per-lane swizzled offset shared by ALL K/V/Q fragment reads:
  // logical L = (chunkconst) + lq*64 + quad*16, XOR key = (lq>>1)&7 for all.
  const int kq = (lq*64 + quad*16) ^ (((lq >> 1) & 7) << 4);

  // XCD swizzle: bx%8 = XCD; 2 (b,kvh) combos per XCD
  int bx = blockIdx.x;
  int g = bx & 7, ii = bx >> 3;
  int combo = g*2 + (ii >> 6);
  int b = combo >> 3, kvh = combo & 7;
  int rr = ii & 63;
  int h   = kvh*4 + (rr & 3);
  int qbp = rr >> 2;

  const u16* Kr = ws + (b*HKV_ + kvh)*S_*D_;
  const u16* Vt = ws + KR_ELEMS + (b*HKV_ + kvh)*D_*S_;

  // staging sources (linear LDS dest, inverse-swizzled global source — rule #21)
  const int aK0 = t*16, aK1 = t*16 + 4096;
  const int lA0 = SWZ(aK0), lA1 = SWZ(aK1);
  const u16* kg0 = Kr + ((lA0 >> 6) & 31)*D_ + (lA0 >> 11)*32 + ((lA0 >> 4) & 3)*8;
  const u16* kg1 = Kr + ((lA1 >> 6) & 31)*D_ + (lA1 >> 11)*32 + ((lA1 >> 4) & 3)*8;
  const u16* vg0 = Vt + (lA0 >> 6)*S_ + ((lA0 >> 4) & 3)*8;
  const u16* vg1 = Vt + (lA1 >> 6)*S_ + ((lA1 >> 4) & 3)*8;

#define STAGE(bufbyte, n0v) do {                                   \
    gload16(kg0 + (n0v)*D_, (u16*)(ldsc + (bufbyte) + aK0));       \
    gload16(kg1 + (n0v)*D_, (u16*)(ldsc + (bufbyte) + aK1));       \
    gload16(vg0 + (n0v),    (u16*)(ldsc + (bufbyte) + 8192 + aK0));\
    gload16(vg1 + (n0v),    (u16*)(ldsc + (bufbyte) + 8192 + aK1));\
  } while (0)

  for (int half = 0; half < 2; ++half) {
    int qb = half ? (31 - qbp) : qbp;
    int q0 = qb * 64;
    if (half) __syncthreads();   // prior inner-loop LDS readers done before Q restage

    // ---- stage Q tile: RoPE + SC2 scale folded in, swizzled stores ----
#pragma unroll
    for (int it = 0; it < 2; ++it) {
      int tp = it*256 + t;
      int row = tp >> 3, j = tp & 7;          // 8 threads/row, 16B loads
      int qbase = ((b*S_ + q0 + row)*HQ_ + h)*D_ + 8*j;
      int cbase = (q0 + row)*D_ + 8*j;
      float a[8], bb[8], cc[8], ssv[8];
      if (f32) {
        const float* qf32 = (const float*)qg;
        f32x4 a0 = *(const f32x4*)(qf32 + qbase);
        f32x4 a1 = *(const f32x4*)(qf32 + qbase + 4);
        f32x4 b0 = *(const f32x4*)(qf32 + qbase + 64);
        f32x4 b1 = *(const f32x4*)(qf32 + qbase + 68);
        f32x4 c0 = *(const f32x4*)((const float*)cs + cbase);
        f32x4 c1 = *(const f32x4*)((const float*)cs + cbase + 4);
        f32x4 s0 = *(const f32x4*)((const float*)sn + cbase);
        f32x4 s1 = *(const f32x4*)((const float*)sn + cbase + 4);
#pragma unroll
        for (int e = 0; e < 4; ++e) {
          a[e] = a0[e];  a[4+e] = a1[e];  bb[e] = b0[e]; bb[4+e] = b1[e];
          cc[e] = c0[e]; cc[4+e] = c1[e]; ssv[e] = s0[e]; ssv[4+e] = s1[e];
        }
      } else {
        const u16* qb16 = (const u16*)qg;
        u16x8 xa = *(const u16x8*)(qb16 + qbase);
        u16x8 xb = *(const u16x8*)(qb16 + qbase + 64);
        u16x8 cv = *(const u16x8*)((const u16*)cs + cbase);
        u16x8 sv = *(const u16x8*)((const u16*)sn + cbase);
#pragma unroll
        for (int e = 0; e < 8; ++e) {
          a[e] = b2f(xa[e]); bb[e] = b2f(xb[e]);
          cc[e] = b2f(cv[e]); ssv[e] = b2f(sv[e]);
        }
      }
      u16 o0[8], o1[8];
#pragma unroll
      for (int e = 0; e < 8; ++e) {
        float C2 = cc[e]*SC2, S2 = ssv[e]*SC2;
        o0[e] = f2b(a[e]*C2 - bb[e]*S2);    // d = 8j+e   (pre-scaled)
        o1[e] = f2b(bb[e]*C2 + a[e]*S2);    // d = 64+8j+e
      }
      int A0 = (j >> 2)*4096 + row*64 + (j & 3)*16;   // logical byte
      int A1 = A0 + 8192;
      *(u16x8*)(ldsc + SWZ(A0)) = *(u16x8*)o0;
      *(u16x8*)(ldsc + SWZ(A1)) = *(u16x8*)o1;
    }
    __syncthreads();
    bf16x8 qf[4];
#pragma unroll
    for (int c = 0; c < 4; ++c)
      qf[c] = *(const bf16x8*)(ldsc + c*4096 + w*1024 + kq);
    asm volatile("s_waitcnt lgkmcnt(0)" ::: "memory");   // Q in regs
    __syncthreads();                                     // ...for ALL waves

    f32x4 o[8];
#pragma unroll
    for (int dt = 0; dt < 8; ++dt) o[dt] = (f32x4){0.f, 0.f, 0.f, 0.f};
    float m_i = -1e30f, l_i = 0.f;
    const int qrow = q0 + w*16 + lq;
    const int nkb = 2*qb + 2;              // causal: keys [0, q0+64)

    // prologue: tile 0 -> buf0, drain, sync (overwrites Q region: consumed)
    STAGE(0, 0);
    asm volatile("s_waitcnt vmcnt(0)" ::: "memory");
    __builtin_amdgcn_s_barrier();
    asm volatile("" ::: "memory");

    int cur = 0;
    for (int kb = 0; kb < nkb; ++kb) {
      // (1) issue next tile's loads first: in flight across the whole compute
      if (kb + 1 < nkb) STAGE((cur ^ 1) << 14, (kb + 1)*32);
      asm volatile("" ::: "memory");       // pin STAGE before compute

      const int n0 = kb * 32;
      const char* tb = ldsc + (cur << 14) + kq;   // single per-iter base

      // ---- S^T = K Q^T (scores arrive pre-scaled, log2 domain) ----
      f32x4 sc0 = {0,0,0,0}, sc1 = {0,0,0,0};
      __builtin_amdgcn_s_setprio(1);
#pragma unroll
      for (int c = 0; c < 4; ++c) {
        bf16x8 k0 = *(const bf16x8*)(tb + c*2048);
        bf16x8 k1 = *(const bf16x8*)(tb + c*2048 + 1024);
        sc0 = __builtin_amdgcn_mfma_f32_16x16x32_bf16(k0, qf[c], sc0, 0, 0, 0);
        sc1 = __builtin_amdgcn_mfma_f32_16x16x32_bf16(k1, qf[c], sc1, 0, 0, 0);
      }
      __builtin_amdgcn_s_setprio(0);

      // ---- online softmax (per-lane scalars; mask only on diagonal tiles) ----
      float s0[4], s1[4];
#pragma unroll
      for (int r = 0; r < 4; ++r) { s0[r] = sc0[r]; s1[r] = sc1[r]; }
      if (kb >= 2*qb) {                    // only last 2 iters cross the diagonal
        const int kk = n0 + quad*4;
#pragma unroll
        for (int r = 0; r < 4; ++r) {
          if (kk + r      > qrow) s0[r] = -1e30f;
          if (kk + 16 + r > qrow) s1[r] = -1e30f;
        }
      }
      float mx = fmaxf(fmaxf(fmaxf(s0[0], s0[1]), fmaxf(s0[2], s0[3])),
                       fmaxf(fmaxf(s1[0], s1[1]), fmaxf(s1[2], s1[3])));
      mx = qredmax(mx);                    // column max across the 4 quads
      // T13 defer-rescale: 11.5 (log2) == 8 nats; P bounded by 2^11.5, f32 O ok
      if (!__all(mx - m_i <= 11.5f)) {
        float mn = fmaxf(m_i, mx);
        float al = EXP2(m_i - mn);
        l_i *= al;
#pragma unroll
        for (int dt = 0; dt < 8; ++dt) {
#pragma unroll
          for (int r = 0; r < 4; ++r) o[dt][r] *= al;
        }
        m_i = mn;
      }
      float p0[4], p1[4];
      float rs = 0.f;
#pragma unroll
      for (int r = 0; r < 4; ++r) {
        p0[r] = EXP2(s0[r] - m_i);
        p1[r] = EXP2(s1[r] - m_i);
        rs += p0[r] + p1[r];
      }
      l_i += qredsum(rs);

      // ---- P^T in-register (proven R4 sequence) ----
      u32 Y0 = cvtpk(p0[0], p0[1]), Y1 = cvtpk(p0[2], p0[3]);
      u32 Z0 = cvtpk(p1[0], p1[1]), Z1 = cvtpk(p1[2], p1[3]);
      pl32(Y0, Z0); pl16(Y0, Z0);          // Y0 = w0, Z0 = w2
      pl32(Y1, Z1); pl16(Y1, Z1);          // Y1 = w1, Z1 = w3
      union { u32 wd[4]; bf16x8 v; } pu;
      pu.wd[0] = Y0; pu.wd[1] = Y1; pu.wd[2] = Z0; pu.wd[3] = Z1;
      bf16x8 pf = pu.v;

      // ---- O^T += V^T P^T ----
      __builtin_amdgcn_s_setprio(1);
#pragma unroll
      for (int dt = 0; dt < 8; ++dt) {
        bf16x8 vf = *(const bf16x8*)(tb + 8192 + dt*1024);
        o[dt] = __builtin_amdgcn_mfma_f32_16x16x32_bf16(vf, pf, o[dt], 0, 0, 0);
      }
      __builtin_amdgcn_s_setprio(0);

      // (2) single end-of-iter sync: my kb+1 loads landed (hidden under
      // compute) + all waves done reading buf[cur] -> next iter may overwrite
      asm volatile("s_waitcnt vmcnt(0) lgkmcnt(0)" ::: "memory");
      __builtin_amdgcn_s_barrier();
      asm volatile("" ::: "memory");
      cur ^= 1;
    }

    // ---- epilogue: O^T/l -> out [B][S][HQ][D] f32; 4 consecutive d per lane ----
    float inv = 1.0f / l_i;
    float* op = out + ((b*S_ + qrow)*HQ_ + h)*D_ + quad*4;
#pragma unroll
    for (int dt = 0; dt < 8; ++dt) {
      f32x4 v = { o[dt][0]*inv, o[dt][1]*inv, o[dt][2]*inv, o[dt][3]*inv };
      *(f32x4*)(op + dt*16) = v;
    }
  }
#undef STAGE
}

extern "C" void kernel_launch(void* const* d_in, const int* in_sizes, int n_in,
                              void* d_out, int out_size, void* d_ws, size_t ws_size,
                              hipStream_t stream) {
  const void* q  = d_in[0];
  const void* k  = d_in[1];
  const void* v  = d_in[2];
  const void* cs = d_in[3];
  const void* sn = d_in[4];
  // d_in[5] (mask) and d_in[6] (scale) are applied analytically in-kernel.
  u16*   ws  = (u16*)d_ws;     // needs 16.8 MB
  float* out = (float*)d_out;  // reference output dtype is float32

  rope_pre<<<KT_BLOCKS + VT_BLOCKS, 256, 0, stream>>>(k, v, cs, sn, ws);
  flash_attn<<<B_*HQ_*(S_/128), 256, 0, stream>>>(q, cs, sn, ws, out);
}

// Round 7
// 243.719 us; speedup vs baseline: 1.0845x; 1.0511x over previous
//
#include <hip/hip_runtime.h>
#include <stdint.h>

typedef unsigned short u16;
typedef unsigned int   u32;
typedef short bf16x8 __attribute__((ext_vector_type(8)));   // 8 bf16 in 4 VGPRs
typedef u16   u16x8  __attribute__((ext_vector_type(8)));
typedef u16   u16x4  __attribute__((ext_vector_type(4)));
typedef float f32x4  __attribute__((ext_vector_type(4)));

#define B_   2
#define S_   2048
#define HQ_  32
#define HKV_ 8
#define D_   128
// SCALE * log2(e): scores computed directly in log2 domain (exp -> v_exp_f32)
#define SC2  0.1275174457530659f

// workspace (bf16 elems, 16.8 MB): Kr [B][HKV][S][D] roped K; Vt [B][HKV][D][S]
#define KR_ELEMS (B_*HKV_*S_*D_)

#define KT_BLOCKS ((B_*S_*HKV_*16) / 256)     // 2048
#define VT_BLOCKS (B_*HKV_*(S_/64))           // 512

// XOR swizzle on LDS byte offsets: key = row bits [9:7] -> flip slot bits [6:4].
#define SWZ(x) ((x) ^ (((x) >> 3) & 0x70))

__device__ __forceinline__ float b2f(u16 x) { return __uint_as_float(((u32)x) << 16); }
__device__ __forceinline__ u16 f2b(float f) {
  u32 u = __float_as_uint(f);
  return (u16)((u + 0x7FFFu + ((u >> 16) & 1u)) >> 16);   // RTNE
}
__device__ __forceinline__ bool is_f32(const void* cs) {
  return ((const u32*)cs)[0] == 0x3F800000u;   // cos[0][0] == 1.0f
}

#if __has_builtin(__builtin_amdgcn_exp2f)
#define EXP2(x) __builtin_amdgcn_exp2f(x)
#else
#define EXP2(x) exp2f(x)
#endif

// gfx950 dual-dest lane swaps. Builtin returns {new_vdst, new_vsrc}.
// Semantics (HW-verified R4 pass):
//   v_permlane32_swap a,b: a' = [a0,a1,b0,b1], b' = [a2,a3,b2,b3]  (16-lane quads)
//   v_permlane16_swap a,b: a' = [a0,b0,a2,b2], b' = [a1,b1,a3,b3]
__device__ __forceinline__ void pl32(u32& a, u32& b) {
  auto r = __builtin_amdgcn_permlane32_swap((int)a, (int)b, false, false);
  a = (u32)r[0]; b = (u32)r[1];
}
__device__ __forceinline__ void pl16(u32& a, u32& b) {
  auto r = __builtin_amdgcn_permlane16_swap((int)a, (int)b, false, false);
  a = (u32)r[0]; b = (u32)r[1];
}
// cross-quad reductions (lanes lq, lq+16, lq+32, lq+48) without ds ops
__device__ __forceinline__ float qredmax(float x) {
  u32 a = __float_as_uint(x), b = a;
  pl16(a, b);
  float m = fmaxf(__uint_as_float(a), __uint_as_float(b));
  u32 c = __float_as_uint(m), d = c;
  pl32(c, d);
  return fmaxf(__uint_as_float(c), __uint_as_float(d));
}
__device__ __forceinline__ float qredsum(float x) {
  u32 a = __float_as_uint(x), b = a;
  pl16(a, b);
  float m = __uint_as_float(a) + __uint_as_float(b);
  u32 c = __float_as_uint(m), d = c;
  pl32(c, d);
  return __uint_as_float(c) + __uint_as_float(d);
}
__device__ __forceinline__ u32 cvtpk(float lo, float hi) {
  u32 r;
  asm("v_cvt_pk_bf16_f32 %0, %1, %2" : "=v"(r) : "v"(lo), "v"(hi));
  return r;
}
// P^T 32-key pack (R4-proven): p0 = keys quad*4+r, p1 = keys 16+quad*4+r
// -> B-fragment words for keys quad*8..quad*8+7 of this 32-key tile.
__device__ __forceinline__ bf16x8 pack_pt(const float* p0, const float* p1) {
  u32 Y0 = cvtpk(p0[0], p0[1]), Y1 = cvtpk(p0[2], p0[3]);
  u32 Z0 = cvtpk(p1[0], p1[1]), Z1 = cvtpk(p1[2], p1[3]);
  pl32(Y0, Z0); pl16(Y0, Z0);          // Y0 = w0, Z0 = w2
  pl32(Y1, Z1); pl16(Y1, Z1);          // Y1 = w1, Z1 = w3
  union { u32 wd[4]; bf16x8 v; } pu;
  pu.wd[0] = Y0; pu.wd[1] = Y1; pu.wd[2] = Z0; pu.wd[3] = Z1;
  return pu.v;
}

__device__ __forceinline__ void gload16(const u16* g, u16* l) {
  __builtin_amdgcn_global_load_lds(
      (const __attribute__((address_space(1))) u32*)g,
      (__attribute__((address_space(3))) u32*)l, 16, 0, 0);
}

// ---------------- pre-pass: RoPE(K) -> Kr, transpose(V) -> Vt (both bf16) ----
__global__ __launch_bounds__(256) void rope_pre(
    const void* __restrict__ kin, const void* __restrict__ vin,
    const void* __restrict__ cs, const void* __restrict__ sn, u16* __restrict__ ws)
{
  const bool f32 = is_f32(cs);
  const int bx = blockIdx.x;
  const int t  = threadIdx.x;
  __shared__ u16 tile[64 * 136];   // V transpose tile, pad 136

  if (bx < KT_BLOCKS) {
    int tid = bx*256 + t;
    int j4 = tid & 15;                 // d2 = 4*j4 .. +3
    int s  = (tid >> 4) & (S_ - 1);
    int h  = (tid >> 15) & (HKV_ - 1);
    int b  = tid >> 18;
    int gi = ((b*S_ + s)*HKV_ + h)*D_ + 4*j4;
    int ci = s*D_ + 4*j4;
    float xa[4], xb[4], c[4], si[4];
    if (f32) {
      const float* kf = (const float*)kin;
      f32x4 a0 = *(const f32x4*)(kf + gi);
      f32x4 b0 = *(const f32x4*)(kf + gi + 64);
      f32x4 c0 = *(const f32x4*)((const float*)cs + ci);
      f32x4 s0 = *(const f32x4*)((const float*)sn + ci);
#pragma unroll
      for (int e = 0; e < 4; ++e) { xa[e]=a0[e]; xb[e]=b0[e]; c[e]=c0[e]; si[e]=s0[e]; }
    } else {
      const u16* kb16 = (const u16*)kin;
      u16x4 a0 = *(const u16x4*)(kb16 + gi);
      u16x4 b0 = *(const u16x4*)(kb16 + gi + 64);
      u16x4 c0 = *(const u16x4*)((const u16*)cs + ci);
      u16x4 s0 = *(const u16x4*)((const u16*)sn + ci);
#pragma unroll
      for (int e = 0; e < 4; ++e) { xa[e]=b2f(a0[e]); xb[e]=b2f(b0[e]); c[e]=b2f(c0[e]); si[e]=b2f(s0[e]); }
    }
    u16 o0[4], o1[4];
#pragma unroll
    for (int e = 0; e < 4; ++e) {
      o0[e] = f2b(xa[e]*c[e] - xb[e]*si[e]);   // d < 64
      o1[e] = f2b(xb[e]*c[e] + xa[e]*si[e]);   // d >= 64 (cos[d]==cos[d+64])
    }
    int oi = ((b*HKV_ + h)*S_ + s)*D_ + 4*j4;
    *(u16x4*)(ws + oi)      = *(u16x4*)o0;
    *(u16x4*)(ws + oi + 64) = *(u16x4*)o1;
  } else {
    int vb = bx - KT_BLOCKS;           // 0..511
    int sb = vb & 31;                  // 64-row s-block
    int h  = (vb >> 5) & (HKV_ - 1);
    int b  = vb >> 8;
    int s0 = sb * 64;
#pragma unroll
    for (int it = 0; it < 8; ++it) {
      int task = it*256 + t;           // 2048 = 64 rows x 32 col-groups
      int c4 = task & 31;
      int r  = task >> 5;
      int gi = ((b*S_ + s0 + r)*HKV_ + h)*D_ + 4*c4;
      u16 e[4];
      if (f32) {
        f32x4 a = *(const f32x4*)((const float*)vin + gi);
#pragma unroll
        for (int j = 0; j < 4; ++j) e[j] = f2b(a[j]);
      } else {
        u16x4 a = *(const u16x4*)((const u16*)vin + gi);
#pragma unroll
        for (int j = 0; j < 4; ++j) e[j] = a[j];
      }
      *(u16x4*)&tile[r*136 + 4*c4] = *(u16x4*)e;
    }
    __syncthreads();
    u32* vtd = (u32*)(ws + KR_ELEMS) + (b*HKV_ + h)*D_*(S_/2);
#pragma unroll
    for (int it = 0; it < 16; ++it) {
      int task = it*256 + t;           // 4096 = 128 d x 32 sp
      int sp = task & 31, d = task >> 5;
      u32 lo = tile[(2*sp)*136 + d];
      u32 hi = tile[(2*sp + 1)*136 + d];
      vtd[d*(S_/2) + s0/2 + sp] = lo | (hi << 16);
    }
  }
}

// ---------------- flash attention, S^T formulation, 32q/wave ----------------
// 512 blocks x 4 waves. Block = paired 128-row Q-tiles {qtp, 15-qtp} processed
// sequentially -> uniform 34 iterations of 64-key tiles (2 R6-identical 32-key
// sub-tiles kt). Wave w owns rows 32w..32w+31 as two 16q groups (A,B) sharing
// every K/V fragment read -> LDS fragment traffic per query HALVED vs R6.
// Per-wave early-out past its diagonal; exact per-element mask only AT it.
__global__ __launch_bounds__(256, 2) void flash_attn(
    const void* __restrict__ qg, const void* __restrict__ cs, const void* __restrict__ sn,
    const u16* __restrict__ ws, float* __restrict__ out)
{
  // LDS bytes: buf p at p*32768: K [2kt][4c][32key][32e] @ +0 (16KB),
  //            V [2kt][128d][32k] @ +16384 (16KB).  Total 64KB -> 2 blocks/CU.
  // Q staging [4c][128row][32e] (32KB) overlaps buf0, consumed pre-loop.
  __shared__ __attribute__((aligned(16))) u16 lds[32768];
  char* ldsc = (char*)lds;

  const bool f32 = is_f32(cs);
  const int t = threadIdx.x;
  const int lane = t & 63, w = t >> 6;
  const int lq = lane & 15, quad = lane >> 4;

  // One per-lane swizzled offset shared by ALL K/V/Q fragment reads: every
  // logical address is (const) + row*64 + quad*16 with row = 16k + lq, so the
  // XOR key (lq>>1)&7 and the +quad*16 term are invariant across sub-tiles.
  const int kq = (lq*64 + quad*16) ^ (((lq >> 1) & 7) << 4);

  // XCD swizzle: bx%8 = XCD; 2 (b,kvh) combos per XCD (512 blocks, bijective)
  int bx = blockIdx.x;
  int g = bx & 7, ii = bx >> 3;        // ii: 0..63
  int combo = g*2 + (ii >> 5);
  int b = combo >> 3, kvh = combo & 7;
  int rr = ii & 31;
  int h   = kvh*4 + (rr & 3);
  int qtp = rr >> 2;                   // 0..7 -> paired {qtp, 15-qtp}

  const u16* Kr = ws + (b*HKV_ + kvh)*S_*D_;
  const u16* Vt = ws + KR_ELEMS + (b*HKV_ + kvh)*D_*S_;

  // staging sources (linear LDS dest, inverse-swizzled global source).
  // Each thread stages 8x16B: 4 into the K region, 4 into the V region.
  const int base = t*16;
  const u16* kgp[4];
  const u16* vgp[4];
#pragma unroll
  for (int i = 0; i < 4; ++i) {
    int a = base + i*4096;             // region-local linear byte
    int l = SWZ(a);                    // logical byte this slot must hold
    int kkt = l >> 13, kc = (l >> 11) & 3, kkey = (l >> 6) & 31, ke = (l >> 4) & 3;
    kgp[i] = Kr + (kkt*32 + kkey)*D_ + kc*32 + ke*8;
    int vkt = l >> 13, vd = (l >> 6) & 127, vk = (l >> 4) & 3;
    vgp[i] = Vt + vd*S_ + vkt*32 + vk*8;
  }

#define STAGE(bufbyte, n0v) do {                                            \
    _Pragma("unroll")                                                       \
    for (int i_ = 0; i_ < 4; ++i_) {                                        \
      gload16(kgp[i_] + (n0v)*D_,                                           \
              (u16*)(ldsc + (bufbyte) + base + i_*4096));                   \
      gload16(vgp[i_] + (n0v),                                              \
              (u16*)(ldsc + (bufbyte) + 16384 + base + i_*4096));           \
    }                                                                       \
  } while (0)

  for (int half = 0; half < 2; ++half) {
    int qt = half ? (15 - qtp) : qtp;
    int q0 = qt * 128;
    if (half) __syncthreads();   // prior inner-loop LDS readers done (safety)

    // ---- stage 128-row Q tile: RoPE + SC2 folded in, swizzled stores ----
#pragma unroll
    for (int it = 0; it < 4; ++it) {
      int tp = it*256 + t;
      int row = tp >> 3, j = tp & 7;          // 8 threads/row, 16B loads
      int qbase = ((b*S_ + q0 + row)*HQ_ + h)*D_ + 8*j;
      int cbase = (q0 + row)*D_ + 8*j;
      float a[8], bb[8], cc[8], ssv[8];
      if (f32) {
        const float* qf32 = (const float*)qg;
        f32x4 a0 = *(const f32x4*)(qf32 + qbase);
        f32x4 a1 = *(const f32x4*)(qf32 + qbase + 4);
        f32x4 b0 = *(const f32x4*)(qf32 + qbase + 64);
        f32x4 b1 = *(const f32x4*)(qf32 + qbase + 68);
        f32x4 c0 = *(const f32x4*)((const float*)cs + cbase);
        f32x4 c1 = *(const f32x4*)((const float*)cs + cbase + 4);
        f32x4 s0 = *(const f32x4*)((const float*)sn + cbase);
        f32x4 s1 = *(const f32x4*)((const float*)sn + cbase + 4);
#pragma unroll
        for (int e = 0; e < 4; ++e) {
          a[e] = a0[e];  a[4+e] = a1[e];  bb[e] = b0[e]; bb[4+e] = b1[e];
          cc[e] = c0[e]; cc[4+e] = c1[e]; ssv[e] = s0[e]; ssv[4+e] = s1[e];
        }
      } else {
        const u16* qb16 = (const u16*)qg;
        u16x8 xa = *(const u16x8*)(qb16 + qbase);
        u16x8 xb = *(const u16x8*)(qb16 + qbase + 64);
        u16x8 cv = *(const u16x8*)((const u16*)cs + cbase);
        u16x8 sv = *(const u16x8*)((const u16*)sn + cbase);
#pragma unroll
        for (int e = 0; e < 8; ++e) {
          a[e] = b2f(xa[e]); bb[e] = b2f(xb[e]);
          cc[e] = b2f(cv[e]); ssv[e] = b2f(sv[e]);
        }
      }
      u16 o0[8], o1[8];
#pragma unroll
      for (int e = 0; e < 8; ++e) {
        float C2 = cc[e]*SC2, S2 = ssv[e]*SC2;
        o0[e] = f2b(a[e]*C2 - bb[e]*S2);    // d = 8j+e   (pre-scaled)
        o1[e] = f2b(bb[e]*C2 + a[e]*S2);    // d = 64+8j+e
      }
      int A0 = (j >> 2)*8192 + row*64 + (j & 3)*16;   // chunks 0,1
      int A1 = A0 + 16384;                            // chunks 2,3
      *(u16x8*)(ldsc + SWZ(A0)) = *(u16x8*)o0;
      *(u16x8*)(ldsc + SWZ(A1)) = *(u16x8*)o1;
    }
    __syncthreads();
    bf16x8 qfA[4], qfB[4];
#pragma unroll
    for (int c = 0; c < 4; ++c) {
      qfA[c] = *(const bf16x8*)(ldsc + c*8192 + w*2048 + kq);          // rows 32w+lq
      qfB[c] = *(const bf16x8*)(ldsc + c*8192 + w*2048 + 1024 + kq);   // +16
    }
    asm volatile("s_waitcnt lgkmcnt(0)" ::: "memory");   // Q in regs
    __syncthreads();                                     // ...for ALL waves

    f32x4 oA[8], oB[8];
#pragma unroll
    for (int dt = 0; dt < 8; ++dt) { oA[dt] = (f32x4){0,0,0,0}; oB[dt] = (f32x4){0,0,0,0}; }
    float mA = -1e30f, lA = 0.f, mB = -1e30f, lB = 0.f;
    const int qrowA = q0 + 32*w + lq;        // group B row = qrowA + 16
    const int nkb = 2*qt + 2;                // 64-key tiles over [0, q0+128)
    const int kbD = 2*qt + (w >> 1);         // this wave's diagonal tile

    // prologue: tile 0 -> buf0 (overwrites consumed Q region)
    STAGE(0, 0);
    asm volatile("s_waitcnt vmcnt(0)" ::: "memory");
    __builtin_amdgcn_s_barrier();
    asm volatile("" ::: "memory");

    int cur = 0;
    for (int kb = 0; kb < nkb; ++kb) {
      // issue next tile's loads first: in flight across the whole compute
      if (kb + 1 < nkb) STAGE((cur ^ 1) << 15, (kb + 1)*64);
      asm volatile("" ::: "memory");

      if (kb <= kbD) {                       // else fully masked: barrier only
        const int n0 = kb * 64;
        const char* tbk = ldsc + (cur << 15) + kq;
        const char* tbv = tbk + 16384;

        // ---- S^T = K Q^T: 2 kt sub-tiles x 2 key-groups x 4 chunks ----
        f32x4 sA[2][2], sB[2][2];
#pragma unroll
        for (int kt = 0; kt < 2; ++kt)
#pragma unroll
          for (int st = 0; st < 2; ++st) { sA[kt][st] = (f32x4){0,0,0,0}; sB[kt][st] = (f32x4){0,0,0,0}; }
        __builtin_amdgcn_s_setprio(1);
#pragma unroll
        for (int c = 0; c < 4; ++c) {
#pragma unroll
          for (int kt = 0; kt < 2; ++kt) {
            bf16x8 k0 = *(const bf16x8*)(tbk + kt*8192 + c*2048);
            bf16x8 k1 = *(const bf16x8*)(tbk + kt*8192 + c*2048 + 1024);
            sA[kt][0] = __builtin_amdgcn_mfma_f32_16x16x32_bf16(k0, qfA[c], sA[kt][0], 0, 0, 0);
            sA[kt][1] = __builtin_amdgcn_mfma_f32_16x16x32_bf16(k1, qfA[c], sA[kt][1], 0, 0, 0);
            sB[kt][0] = __builtin_amdgcn_mfma_f32_16x16x32_bf16(k0, qfB[c], sB[kt][0], 0, 0, 0);
            sB[kt][1] = __builtin_amdgcn_mfma_f32_16x16x32_bf16(k1, qfB[c], sB[kt][1], 0, 0, 0);
          }
        }
        __builtin_amdgcn_s_setprio(0);

        // ---- exact causal mask only on the diagonal tile ----
        if (kb == kbD) {
#pragma unroll
          for (int kt = 0; kt < 2; ++kt)
#pragma unroll
            for (int st = 0; st < 2; ++st)
#pragma unroll
              for (int r = 0; r < 4; ++r) {
                int key = n0 + kt*32 + st*16 + quad*4 + r;
                if (key > qrowA)      sA[kt][st][r] = -1e30f;
                if (key > qrowA + 16) sB[kt][st][r] = -1e30f;
              }
        }

        // ---- online softmax per group ----
        float mxA = -1e30f, mxB = -1e30f;
#pragma unroll
        for (int kt = 0; kt < 2; ++kt)
#pragma unroll
          for (int st = 0; st < 2; ++st)
#pragma unroll
            for (int r = 0; r < 4; ++r) {
              mxA = fmaxf(mxA, sA[kt][st][r]);
              mxB = fmaxf(mxB, sB[kt][st][r]);
            }
        mxA = qredmax(mxA);
        mxB = qredmax(mxB);
        // T13 defer-rescale: 11.5 (log2) == 8 nats
        if (!__all((mxA - mA <= 11.5f) && (mxB - mB <= 11.5f))) {
          float mnA = fmaxf(mA, mxA), alA = EXP2(mA - mnA);
          float mnB = fmaxf(mB, mxB), alB = EXP2(mB - mnB);
          lA *= alA; lB *= alB;
#pragma unroll
          for (int dt = 0; dt < 8; ++dt)
#pragma unroll
            for (int r = 0; r < 4; ++r) { oA[dt][r] *= alA; oB[dt][r] *= alB; }
          mA = mnA; mB = mnB;
        }
        float pA[2][2][4], pB[2][2][4];
        float rsA = 0.f, rsB = 0.f;
#pragma unroll
        for (int kt = 0; kt < 2; ++kt)
#pragma unroll
          for (int st = 0; st < 2; ++st)
#pragma unroll
            for (int r = 0; r < 4; ++r) {
              pA[kt][st][r] = EXP2(sA[kt][st][r] - mA);
              pB[kt][st][r] = EXP2(sB[kt][st][r] - mB);
              rsA += pA[kt][st][r];
              rsB += pB[kt][st][r];
            }
        lA += qredsum(rsA);
        lB += qredsum(rsB);

        // ---- P^T in-register packs (R4-proven), per group per kt ----
        bf16x8 pfA0 = pack_pt(pA[0][0], pA[0][1]);
        bf16x8 pfA1 = pack_pt(pA[1][0], pA[1][1]);
        bf16x8 pfB0 = pack_pt(pB[0][0], pB[0][1]);
        bf16x8 pfB1 = pack_pt(pB[1][0], pB[1][1]);

        // ---- O^T += V^T P^T: each V fragment feeds BOTH groups ----
        __builtin_amdgcn_s_setprio(1);
#pragma unroll
        for (int dt = 0; dt < 8; ++dt) {
          bf16x8 v0 = *(const bf16x8*)(tbv + dt*1024);
          bf16x8 v1 = *(const bf16x8*)(tbv + 8192 + dt*1024);
          oA[dt] = __builtin_amdgcn_mfma_f32_16x16x32_bf16(v0, pfA0, oA[dt], 0, 0, 0);
          oB[dt] = __builtin_amdgcn_mfma_f32_16x16x32_bf16(v0, pfB0, oB[dt], 0, 0, 0);
          oA[dt] = __builtin_amdgcn_mfma_f32_16x16x32_bf16(v1, pfA1, oA[dt], 0, 0, 0);
          oB[dt] = __builtin_amdgcn_mfma_f32_16x16x32_bf16(v1, pfB1, oB[dt], 0, 0, 0);
        }
        __builtin_amdgcn_s_setprio(0);
      }

      // single end-of-iter sync: my next-tile loads landed (hidden under
      // compute) + all waves done reading buf[cur]
      asm volatile("s_waitcnt vmcnt(0) lgkmcnt(0)" ::: "memory");
      __builtin_amdgcn_s_barrier();
      asm volatile("" ::: "memory");
      cur ^= 1;
    }

    // ---- epilogue: O^T/l -> out [B][S][HQ][D] f32 ----
    float invA = 1.0f / lA, invB = 1.0f / lB;
    float* opA = out + ((b*S_ + qrowA)*HQ_ + h)*D_ + quad*4;
    float* opB = opA + 16*HQ_*D_;          // row qrowA + 16
#pragma unroll
    for (int dt = 0; dt < 8; ++dt) {
      f32x4 va = { oA[dt][0]*invA, oA[dt][1]*invA, oA[dt][2]*invA, oA[dt][3]*invA };
      f32x4 vb = { oB[dt][0]*invB, oB[dt][1]*invB, oB[dt][2]*invB, oB[dt][3]*invB };
      *(f32x4*)(opA + dt*16) = va;
      *(f32x4*)(opB + dt*16) = vb;
    }
  }
#undef STAGE
}

extern "C" void kernel_launch(void* const* d_in, const int* in_sizes, int n_in,
                              void* d_out, int out_size, void* d_ws, size_t ws_size,
                              hipStream_t stream) {
  const void* q  = d_in[0];
  const void* k  = d_in[1];
  const void* v  = d_in[2];
  const void* cs = d_in[3];
  const void* sn = d_in[4];
  // d_in[5] (mask) and d_in[6] (scale) are applied analytically in-kernel.
  u16*   ws  = (u16*)d_ws;     // needs 16.8 MB
  float* out = (float*)d_out;  // reference output dtype is float32

  rope_pre<<<KT_BLOCKS + VT_BLOCKS, 256, 0, stream>>>(k, v, cs, sn, ws);
  flash_attn<<<512, 256, 0, stream>>>(q, cs, sn, ws, out);
}